// Round 5
// baseline (190.333 us; speedup 1.0000x reference)
//
#include <hip/hip_runtime.h>

typedef unsigned short u16;
typedef unsigned int u32;
typedef __attribute__((ext_vector_type(8))) short short8;
typedef __attribute__((ext_vector_type(4))) float f32x4;

__device__ __forceinline__ u16 f2bf(float f) {
    union { float f; u32 u; } c; c.f = f;
    u32 u = c.u;
    return (u16)((u + 0x7fffu + ((u >> 16) & 1u)) >> 16);
}

__device__ __forceinline__ u32 pack2(float a, float b) {
    return (u32)f2bf(a) | ((u32)f2bf(b) << 16);
}

#define MFMA16(A, B, C) __builtin_amdgcn_mfma_f32_16x16x32_bf16((A), (B), (C), 0, 0, 0)

// ---------------------------------------------------------------------------
// Weight prepass only (proven ~4 us, rounds 1-2). x is fused into btt_x.
//   W1F [m2][nb][ct][ks][lane][8] : W1[m2][m1=ks*32+q*8+j][c=nb*32+ct*16+lr]
//   W2F [n1][m2b][nt][lane][8]    : W2[n1][k=m2b*32+q*8+j][n2=nt*16+lr]
// (lane = q*16+lr). Grid: 64 + 64 blocks, 256 threads.
// ---------------------------------------------------------------------------
__global__ __launch_bounds__(256) void prep_w(const float* __restrict__ W1,
                                              const float* __restrict__ W2,
                                              u16* __restrict__ W1F,
                                              u16* __restrict__ W2F) {
    __shared__ u16 sh[16384];
    const int bid = blockIdx.x;
    const int t = threadIdx.x;

    if (bid < 64) {
        const int m2 = bid;
        const float4* src = (const float4*)(W1 + (size_t)m2 * 16384);
        #pragma unroll
        for (int s = 0; s < 16; ++s) {
            float4 f = src[s * 256 + t];
            float fv[4] = {f.x, f.y, f.z, f.w};
            #pragma unroll
            for (int e = 0; e < 4; ++e) {
                int elem = (s * 256 + t) * 4 + e;
                int m1 = elem >> 8, c = elem & 255;
                int nb = c >> 5, ct = (c >> 4) & 1, lr = c & 15;
                int ks = m1 >> 5, q = (m1 >> 3) & 3, j = m1 & 7;
                sh[(((((nb * 2 + ct) * 2 + ks) * 4 + q)) << 7) + lr * 8 + j] =
                    f2bf(fv[e]);
            }
        }
        __syncthreads();
        u16* dst = W1F + (size_t)m2 * 16384 + t * 64;
        #pragma unroll
        for (int s = 0; s < 8; ++s)
            *(short8*)(dst + s * 8) = *(const short8*)(&sh[t * 64 + s * 8]);
    } else {
        const int n1 = bid - 64;
        const float4* src = (const float4*)(W2 + (size_t)n1 * 16384);
        #pragma unroll
        for (int s = 0; s < 16; ++s) {
            float4 f = src[s * 256 + t];
            float fv[4] = {f.x, f.y, f.z, f.w};
            #pragma unroll
            for (int e = 0; e < 4; ++e) {
                int elem = (s * 256 + t) * 4 + e;
                int k = elem >> 6, n2 = elem & 63;
                int m2b = k >> 5, q = (k >> 3) & 3, j = k & 7;
                int nt = n2 >> 4, lr = n2 & 15;
                sh[((((m2b * 4 + nt) * 4 + q)) << 7) + lr * 8 + j] = f2bf(fv[e]);
            }
        }
        __syncthreads();
        u16* dst = W2F + (size_t)n1 * 16384 + t * 64;
        #pragma unroll
        for (int s = 0; s < 8; ++s)
            *(short8*)(dst + s * 8) = *(const short8*)(&sh[t * 64 + s * 8]);
    }
}

// ---------------------------------------------------------------------------
// btt_x: round-0/4 proven math core with x FUSED via per-wave contiguous
// loads + wave-private LDS bounce (no XF prepass, no XF traffic).
//  * Each wave loads its own 64x64 x-tile as full 256-B row segments
//    (16 coalesced float4 instrs, full 128-B-line use — the prep_all access
//    shape, NOT rounds 1-2's strided fragment gather that blew FETCH).
//  * f2bf in-register, bounce through per-wave 2-KB scratch in two 32-row
//    halves to produce the exact XF fragment layout. Wave-private: no
//    barriers, only lgkmcnt(0) fences (W->R and R->W on the reused half).
//  * Scratch XOR row-swizzle lr^((ks*4+q)&7) applied on BOTH sides:
//    write ds_write_b64 (lanes spread s=0..7 distinct -> all 32 banks once
//    per row-quad) and read ds_read_b128 (row-perm per q-group, 2-way free).
//  * t_lds single-buffer + 2 barriers (round-4 proved db/1-barrier neutral),
//    LDS total 66,560 B == round-4 footprint -> 2 blocks/CU preserved.
//  * grid 512 (bt=bid&63, nb=bid>>6): same-XCD nb-sharing, per-XCD x window
//    = 8 bt x 64 rows x 2 KB = 1 MB, L2-resident (round-1's grid-1024 drift
//    thrash avoided).
// MFMA mappings / t_lds stride 260 / epilogue identical to HW-proven btt_main.
// ---------------------------------------------------------------------------
__global__ __launch_bounds__(512) void btt_x(const float* __restrict__ x,
                                             const u16* __restrict__ W1F,
                                             const u16* __restrict__ W2F,
                                             float* __restrict__ out) {
    __shared__ u16 t_lds[64 * 260];   // 33,280 B
    __shared__ u16 xscr[8][2080];     // 33,280 B, per-wave 2-KB bounce buffer

    const int tid = threadIdx.x;
    const int w = tid >> 6;       // wave 0..7
    const int lane = tid & 63;
    const int q = lane >> 4;      // quad (== row-within-quad on load side)
    const int lr = lane & 15;
    const int lo = lane & 15;     // float4 index within a 64-col tile row
    const int bt = blockIdx.x & 63;
    const int nb = blockIdx.x >> 6;
    const int n1 = nb * 8 + w;

    // write-side fragment coords, fixed per lane (from lo):
    const int wks = lo >> 3;            // ks of this lane's float4
    const int wq  = (lo >> 1) & 3;      // q  of this lane's float4
    const int wj0 = (lo & 1) * 4;       // j0 (4-col half of the 8-run)
    const int wswz = (wks * 4 + wq) & 7;
    u16* scr = xscr[w];

    const f32x4 fz = {0.f, 0.f, 0.f, 0.f};
    f32x4 acc2[4][4];             // y[b(4x16)][n2(4x16)]
    #pragma unroll
    for (int i = 0; i < 4; ++i)
        #pragma unroll
        for (int j = 0; j < 4; ++j) acc2[i][j] = fz;

    for (int m2b = 0; m2b < 8; ++m2b) {
        const int m2 = m2b * 8 + w;
        // lane's column base within its wave's tile: cols m2*64 + lo*4 ..+3
        const float* xt = x + ((size_t)bt * 64 + q) * 4096 + m2 * 64 + lo * 4;

        // ---- half 0: rows 0..31 of the tile (8 x 4-row loads) ----
        float4 f0[8];
        #pragma unroll
        for (int i8 = 0; i8 < 8; ++i8)
            f0[i8] = *(const float4*)(xt + (size_t)(i8 * 4) * 4096);

        // weights for this iteration (L2/L3-resident), in flight over the
        // whole conversion + MFMA1 phase
        short8 a1[2][2];
        {
            const u16* pw = W1F + ((size_t)m2 * 8 + nb) * 2048 + lane * 8;
            #pragma unroll
            for (int ct = 0; ct < 2; ++ct)
                #pragma unroll
                for (int ks = 0; ks < 2; ++ks)
                    a1[ct][ks] = *(const short8*)(pw + (ct * 2 + ks) * 512);
        }
        short8 b2[4];
        {
            const u16* pw = W2F + (size_t)n1 * 16384 + m2b * 2048 + lane * 8;
            #pragma unroll
            for (int nt = 0; nt < 4; ++nt)
                b2[nt] = *(const short8*)(pw + nt * 512);
        }

        // pack + scatter half 0 into fragment layout (conflict-free b64)
        #pragma unroll
        for (int i8 = 0; i8 < 8; ++i8) {
            int rl = i8 * 4 + q;            // row 0..31
            int bl_l = (rl >> 4) & 1;
            int lrw = rl & 15;
            int off = ((bl_l * 2 + wks) * 4 + wq) * 128 + ((lrw ^ wswz) * 8) + wj0;
            uint2 d = make_uint2(pack2(f0[i8].x, f0[i8].y),
                                 pack2(f0[i8].z, f0[i8].w));
            *(uint2*)(&scr[off]) = d;
        }

        // ---- issue half-1 loads now (latency hidden under h0 LDS traffic) --
        float4 f1[8];
        #pragma unroll
        for (int i8 = 0; i8 < 8; ++i8)
            f1[i8] = *(const float4*)(xt + (size_t)(32 + i8 * 4) * 4096);

        asm volatile("s_waitcnt lgkmcnt(0)" ::: "memory");  // h0 writes visible
        short8 b1[4][2];
        #pragma unroll
        for (int bl = 0; bl < 2; ++bl)
            #pragma unroll
            for (int ks = 0; ks < 2; ++ks) {
                int off = ((bl * 2 + ks) * 4 + q) * 128 +
                          ((lr ^ ((ks * 4 + q) & 7)) * 8);
                b1[bl][ks] = *(const short8*)(&scr[off]);
            }
        asm volatile("s_waitcnt lgkmcnt(0)" ::: "memory");  // h0 reads retired

        // ---- half 1: rows 32..63, reuse the same scratch region ----
        #pragma unroll
        for (int i8 = 0; i8 < 8; ++i8) {
            int rl = 32 + i8 * 4 + q;       // row 32..63
            int bl_l = (rl >> 4) & 1;
            int lrw = rl & 15;
            int off = ((bl_l * 2 + wks) * 4 + wq) * 128 + ((lrw ^ wswz) * 8) + wj0;
            uint2 d = make_uint2(pack2(f1[i8].x, f1[i8].y),
                                 pack2(f1[i8].z, f1[i8].w));
            *(uint2*)(&scr[off]) = d;
        }
        asm volatile("s_waitcnt lgkmcnt(0)" ::: "memory");  // h1 writes visible
        #pragma unroll
        for (int bl = 2; bl < 4; ++bl)
            #pragma unroll
            for (int ks = 0; ks < 2; ++ks) {
                int off = (((bl & 1) * 2 + ks) * 4 + q) * 128 +
                          ((lr ^ ((ks * 4 + q) & 7)) * 8);
                b1[bl][ks] = *(const short8*)(&scr[off]);
            }
        // (compiler inserts the lgkm wait before first MFMA use of b1[2..3])

        // ---- stage 1: tT[c'(32)][b(64)] = W1_slice(32x64) . xT(64x64) ----
        f32x4 acc1[2][4];
        #pragma unroll
        for (int ct = 0; ct < 2; ++ct)
            #pragma unroll
            for (int bl = 0; bl < 4; ++bl) acc1[ct][bl] = fz;
        #pragma unroll
        for (int ks = 0; ks < 2; ++ks)
            #pragma unroll
            for (int ct = 0; ct < 2; ++ct)
                #pragma unroll
                for (int bl = 0; bl < 4; ++bl)
                    acc1[ct][bl] = MFMA16(a1[ct][ks], b1[bl][ks], acc1[ct][bl]);

        __syncthreads();   // prior iteration's stage-2 t reads done

        // tT -> t_lds[b][w*32+c']; D: row=c'=ct*16+q*4+g, col=b=bl*16+lr
        #pragma unroll
        for (int ct = 0; ct < 2; ++ct)
            #pragma unroll
            for (int bl = 0; bl < 4; ++bl) {
                int off = (bl * 16 + lr) * 260 + w * 32 + ct * 16 + q * 4;
                u32 lov = pack2(acc1[ct][bl][0], acc1[ct][bl][1]);
                u32 hiv = pack2(acc1[ct][bl][2], acc1[ct][bl][3]);
                *(uint2*)(&t_lds[off]) = make_uint2(lov, hiv);
            }

        __syncthreads();   // all t written before stage-2 reads

        // ---- stage 2: y[b][n2] += t2(64x32) . W2_slice(32x64) ----
        short8 a2[4];
        #pragma unroll
        for (int bl = 0; bl < 4; ++bl) {
            int base = (bl * 16 + lr) * 260 + (2 * q) * 32 + w * 4;
            union { short8 v; uint2 u[2]; } tmp;
            tmp.u[0] = *(const uint2*)(&t_lds[base]);
            tmp.u[1] = *(const uint2*)(&t_lds[base + 32]);
            a2[bl] = tmp.v;
        }
        #pragma unroll
        for (int bl = 0; bl < 4; ++bl)
            #pragma unroll
            for (int nt = 0; nt < 4; ++nt)
                acc2[bl][nt] = MFMA16(a2[bl], b2[nt], acc2[bl][nt]);
    }

    // ---- epilogue: D rows = b (q*4+g), cols = n2 (lr); fp32 stores ----
    #pragma unroll
    for (int bl = 0; bl < 4; ++bl)
        #pragma unroll
        for (int nt = 0; nt < 4; ++nt)
            #pragma unroll
            for (int g = 0; g < 4; ++g) {
                long row = bt * 64 + bl * 16 + q * 4 + g;
                long col = (long)n1 * 64 + nt * 16 + lr;
                out[row * 4096 + col] = acc2[bl][nt][g];
            }
}

// ---------------------------------------------------------------------------
// Fallback (ws too small): HW-proven scalar-weight-load kernel.
// ---------------------------------------------------------------------------
__global__ __launch_bounds__(512) void btt_nows(const float* __restrict__ x,
                                                const float* __restrict__ W1,
                                                const float* __restrict__ W2,
                                                float* __restrict__ out) {
    __shared__ u16 t_lds[64 * 260];
    const int tid = threadIdx.x;
    const int w = tid >> 6;
    const int lane = tid & 63;
    const int q = lane >> 4;
    const int lr = lane & 15;
    const int bt = blockIdx.x & 63;
    const int nb = blockIdx.x >> 6;
    const int n1 = nb * 8 + w;

    const f32x4 fz = {0.f, 0.f, 0.f, 0.f};
    f32x4 acc2[4][4];
    #pragma unroll
    for (int i = 0; i < 4; ++i)
        #pragma unroll
        for (int j = 0; j < 4; ++j) acc2[i][j] = fz;

    for (int m2b = 0; m2b < 8; ++m2b) {
        const int m2 = m2b * 8 + w;
        short8 ax[4][2];
        #pragma unroll
        for (int bl = 0; bl < 4; ++bl)
            #pragma unroll
            for (int ks = 0; ks < 2; ++ks) {
                const float* p = x + (size_t)(bt * 64 + bl * 16 + lr) * 4096 +
                                 m2 * 64 + ks * 32 + q * 8;
                float4 ua = *(const float4*)(p);
                float4 ub = *(const float4*)(p + 4);
                short8 r;
                r[0] = (short)f2bf(ua.x); r[1] = (short)f2bf(ua.y);
                r[2] = (short)f2bf(ua.z); r[3] = (short)f2bf(ua.w);
                r[4] = (short)f2bf(ub.x); r[5] = (short)f2bf(ub.y);
                r[6] = (short)f2bf(ub.z); r[7] = (short)f2bf(ub.w);
                ax[bl][ks] = r;
            }
        short8 bw1[2][2];
        #pragma unroll
        for (int ct = 0; ct < 2; ++ct)
            #pragma unroll
            for (int ks = 0; ks < 2; ++ks)
                #pragma unroll
                for (int j = 0; j < 8; ++j)
                    bw1[ct][ks][j] = (short)f2bf(W1[m2 * 16384 +
                                                    (ks * 32 + q * 8 + j) * 256 +
                                                    nb * 32 + ct * 16 + lr]);
        f32x4 acc1[4][2];
        #pragma unroll
        for (int bl = 0; bl < 4; ++bl)
            #pragma unroll
            for (int ct = 0; ct < 2; ++ct) acc1[bl][ct] = fz;
        #pragma unroll
        for (int ks = 0; ks < 2; ++ks)
            #pragma unroll
            for (int bl = 0; bl < 4; ++bl)
                #pragma unroll
                for (int ct = 0; ct < 2; ++ct)
                    acc1[bl][ct] = MFMA16(ax[bl][ks], bw1[ct][ks], acc1[bl][ct]);

        __syncthreads();
        #pragma unroll
        for (int bl = 0; bl < 4; ++bl)
            #pragma unroll
            for (int ct = 0; ct < 2; ++ct)
                #pragma unroll
                for (int g = 0; g < 4; ++g)
                    t_lds[(bl * 16 + q * 4 + g) * 260 + w * 32 + ct * 16 + lr] =
                        f2bf(acc1[bl][ct][g]);
        __syncthreads();

        short8 a2[4];
        #pragma unroll
        for (int bl = 0; bl < 4; ++bl) {
            int base = (bl * 16 + lr) * 260 + (2 * q) * 32 + w * 4;
            union { short8 v; uint2 u[2]; } tmp;
            tmp.u[0] = *(const uint2*)(&t_lds[base]);
            tmp.u[1] = *(const uint2*)(&t_lds[base + 32]);
            a2[bl] = tmp.v;
        }
        short8 b2[4];
        #pragma unroll
        for (int nt = 0; nt < 4; ++nt)
            #pragma unroll
            for (int j = 0; j < 8; ++j)
                b2[nt][j] = (short)f2bf(W2[n1 * 16384 +
                                           (m2b * 32 + q * 8 + j) * 64 +
                                           nt * 16 + lr]);
        #pragma unroll
        for (int bl = 0; bl < 4; ++bl)
            #pragma unroll
            for (int nt = 0; nt < 4; ++nt)
                acc2[bl][nt] = MFMA16(a2[bl], b2[nt], acc2[bl][nt]);
    }

    #pragma unroll
    for (int bl = 0; bl < 4; ++bl)
        #pragma unroll
        for (int nt = 0; nt < 4; ++nt)
            #pragma unroll
            for (int g = 0; g < 4; ++g) {
                long row = bt * 64 + bl * 16 + q * 4 + g;
                long col = (long)n1 * 64 + nt * 16 + lr;
                out[row * 4096 + col] = acc2[bl][nt][g];
            }
}

extern "C" void kernel_launch(void* const* d_in, const int* in_sizes, int n_in,
                              void* d_out, int out_size, void* d_ws, size_t ws_size,
                              hipStream_t stream) {
    const float* x  = (const float*)d_in[0];   // (4096, 4096) fp32
    const float* W1 = (const float*)d_in[1];   // (64, 64, 256) fp32
    const float* W2 = (const float*)d_in[2];   // (64, 256, 64) fp32
    float* out = (float*)d_out;

    const size_t N_W1F = (size_t)64 * 16384;          // 2 MiB
    const size_t N_W2F = (size_t)64 * 16384;          // 2 MiB
    const size_t WS_NEED = (N_W1F + N_W2F) * sizeof(u16);  // 4 MiB

    if (ws_size >= WS_NEED) {
        u16* W1F = (u16*)d_ws;
        u16* W2F = W1F + N_W1F;
        prep_w<<<128, 256, 0, stream>>>(W1, W2, W1F, W2F);
        btt_x<<<512, 512, 0, stream>>>(x, W1F, W2F, out);
    } else {
        btt_nows<<<512, 512, 0, stream>>>(x, W1, W2, out);
    }
}